// Round 12
// baseline (65.020 us; speedup 1.0000x reference)
//
#include <hip/hip_runtime.h>

#define TEX_H 256
#define TEX_W 256
#define FCH 16
#define NPIX (8 * 256 * 256)
#define NCELL (256 * 256)
#define CAP 16                // entries per cell (Poisson lambda~4; overflow -> atomic fallback)

#define SQRT2_F 1.41421356237f
// Interior weights (grid anchored at u-2 => du,dv exactly in {0,1,2};
// d=2 slots fail w>0.1, leaving the 3x3 with constant weights):
#define W_EDGE   0.24311673443f   // exp(-sqrt(2))
#define W_DIAG   0.13533528324f   // exp(-2)

// ws layout (float words):
//  halo_c [NCELL*16]      per-cell channel sums
//  halo_n [NCELL]         per-cell counts
//  dir_c  [2*4*256*16]    boundary strips (ui<4 | vi<4)
//  dir_w  [2*4*256]
//  counts [NCELL] (int)   bucket counters
//  entries[NCELL*CAP](u32) bucket entries (no init needed)
#define HALO_C_OFF 0
#define HALO_N_OFF (NCELL * 16)
#define DIR_C_OFF  (HALO_N_OFF + NCELL)
#define DIR_W_OFF  (DIR_C_OFF + 2 * 4 * 256 * 16)
#define CNT_OFF    (DIR_W_OFF + 2 * 4 * 256)
#define ENT_OFF    (CNT_OFF + NCELL)
#define WS_FLOATS  (ENT_OFF + NCELL * CAP)
#define ZERO_FLOATS ENT_OFF          // zero everything except entries

// ---- device helper: exact reference boundary path (u<2 or v<2) ----
__device__ __forceinline__ void boundary_splat(float u, float v, float f, int c,
                                               float* __restrict__ ws) {
    float us = fmaxf(u - 2.0f, 0.0f);
    float vs = fmaxf(v - 2.0f, 0.0f);
    #pragma unroll
    for (int kv = 0; kv < 4; ++kv) {
        float vg = vs + (float)kv;
        int vi = (int)vg;
        float dvf = fabsf(vg - v);
        #pragma unroll
        for (int ku = 0; ku < 4; ++ku) {
            float ug = us + (float)ku;
            int ui = (int)ug;
            float duf = fabsf(ug - u);
            float w = expf(-sqrtf(duf * duf + dvf * dvf) * SQRT2_F);
            if (w > 0.1f && vi < TEX_H && ui < TEX_W) {
                int cell = (ui < 4) ? (ui * 256 + vi)        // region 0 (u<2)
                                    : ((4 + vi) * 256 + ui); // region 1 (vi<4)
                unsafeAtomicAdd(&ws[DIR_C_OFF + cell * FCH + c], w * f);
                if (c == 0) unsafeAtomicAdd(&ws[DIR_W_OFF + cell], w);
            }
        }
    }
}

// ---- bin: 16 lanes per pixel. Interior: lane0 claims a slot in the pixel's
// center cell and stores the pixel id (overflow -> direct r10 atomic path).
// Boundary: exact expf path into edge strips. ----
__global__ __launch_bounds__(256) void bin_kernel(
    const float*  __restrict__ f_map,
    const float2* __restrict__ uv_map,
    const float*  __restrict__ mask,
    float* __restrict__ ws)
{
    int tid = blockIdx.x * 256 + threadIdx.x;
    int pix = tid >> 4;
    int c   = tid & 15;

    if (mask[pix] == 0.0f) return;

    float2 uv = uv_map[pix];
    float u = uv.x * 256.0f;
    float v = uv.y * 256.0f;

    if (u >= 2.0f && v >= 2.0f) {
        int cell = ((int)v) * 256 + (int)u;
        int slot = 0;
        if (c == 0) slot = atomicAdd((int*)ws + CNT_OFF + cell, 1);
        slot = __shfl(slot, 0, 16);           // broadcast lane0's slot to the group
        if (slot < CAP) {
            if (c == 0) ((unsigned*)ws)[ENT_OFF + cell * CAP + slot] = (unsigned)pix;
        } else {
            // rare overflow: direct per-center atomic accumulation (r10 path)
            float f = f_map[pix * FCH + c];
            unsafeAtomicAdd(&ws[HALO_C_OFF + cell * FCH + c], f);
            if (c == 0) unsafeAtomicAdd(&ws[HALO_N_OFF + cell], 1.0f);
        }
    } else {
        float f = f_map[pix * FCH + c];
        boundary_splat(u, v, f, c, ws);
    }
}

// ---- gather: one 16-lane group per cell. Read up to CAP entry ids (one 64B
// line), sum the f-vectors in registers (4-deep independent loads), one
// atomic-add of the per-cell sum into halo. ----
__global__ __launch_bounds__(256) void gather_kernel(
    const float* __restrict__ f_map,
    float* __restrict__ ws)
{
    int tid  = blockIdx.x * 256 + threadIdx.x;
    int cell = tid >> 4;
    int c    = tid & 15;

    int cnt = min(((const int*)ws)[CNT_OFF + cell], CAP);
    if (cnt == 0) return;                       // uniform per group

    unsigned ent = ((const unsigned*)ws)[ENT_OFF + cell * CAP + c];  // lane c = entry c
    float acc = 0.0f;

    int e = 0;
    for (; e + 4 <= cnt; e += 4) {
        unsigned p0 = __shfl(ent, e + 0, 16);
        unsigned p1 = __shfl(ent, e + 1, 16);
        unsigned p2 = __shfl(ent, e + 2, 16);
        unsigned p3 = __shfl(ent, e + 3, 16);
        float f0 = f_map[p0 * FCH + c];
        float f1 = f_map[p1 * FCH + c];
        float f2 = f_map[p2 * FCH + c];
        float f3 = f_map[p3 * FCH + c];
        acc += f0; acc += f1; acc += f2; acc += f3;
    }
    for (; e < cnt; ++e) {
        unsigned p = __shfl(ent, e, 16);
        acc += f_map[p * FCH + c];
    }

    unsafeAtomicAdd(&ws[HALO_C_OFF + cell * FCH + c], acc);
    if (c == 0) unsafeAtomicAdd(&ws[HALO_N_OFF + cell], (float)cnt);
}

// ---- fallback splat (proven r10 path) when ws is too small for buckets ----
__global__ __launch_bounds__(256) void splat_kernel(
    const float*  __restrict__ f_map,
    const float2* __restrict__ uv_map,
    const float*  __restrict__ mask,
    float* __restrict__ ws)
{
    int tid = blockIdx.x * 256 + threadIdx.x;
    int pix = tid >> 4;
    int c   = tid & 15;

    if (mask[pix] == 0.0f) return;

    float2 uv = uv_map[pix];
    float u = uv.x * 256.0f;
    float v = uv.y * 256.0f;
    float f = f_map[pix * FCH + c];

    if (u >= 2.0f && v >= 2.0f) {
        int cell = ((int)v) * 256 + (int)u;
        unsafeAtomicAdd(&ws[HALO_C_OFF + cell * FCH + c], f);
        if (c == 0) unsafeAtomicAdd(&ws[HALO_N_OFF + cell], 1.0f);
    } else {
        boundary_splat(u, v, f, c, ws);
    }
}

// ---- finalize: 3x3 const-weight conv of per-cell sums (+ strips), normalize,
// write 8 broadcast copies. (verified in r10) ----
__global__ __launch_bounds__(256) void finalize_kernel(
    const float* __restrict__ ws,
    float* __restrict__ out)
{
    int tile = blockIdx.x;                  // 32x32 tiles of 8x8
    int r0 = (tile >> 5) << 3;
    int c0 = (tile & 31) << 3;
    int tx = threadIdx.x >> 2;              // texel in tile 0..63
    int c4 = threadIdx.x & 3;               // float4 chunk 0..3
    int gr = r0 + (tx >> 3);
    int gc = c0 + (tx & 7);

    float4 cs = make_float4(0.f, 0.f, 0.f, 0.f);
    float wsm = 0.0f;

    #pragma unroll
    for (int a = -1; a <= 1; ++a) {
        int cr = gr + a;
        if (cr < 0 || cr > 255) continue;
        #pragma unroll
        for (int b = -1; b <= 1; ++b) {
            int cc = gc + b;
            if (cc < 0 || cc > 255) continue;
            float w = (a == 0 && b == 0) ? 1.0f
                    : ((a == 0 || b == 0) ? W_EDGE : W_DIAG);
            int cell = cr * 256 + cc;
            float4 h = *(const float4*)&ws[HALO_C_OFF + cell * FCH + c4 * 4];
            cs.x += w * h.x; cs.y += w * h.y; cs.z += w * h.z; cs.w += w * h.w;
            wsm  += w * ws[HALO_N_OFF + cell];
        }
    }

    if (gc < 4) {
        int cell = gc * 256 + gr;
        float4 d = *(const float4*)&ws[DIR_C_OFF + cell * FCH + c4 * 4];
        cs.x += d.x; cs.y += d.y; cs.z += d.z; cs.w += d.w;
        wsm  += ws[DIR_W_OFF + cell];
    } else if (gr < 4) {
        int cell = (4 + gr) * 256 + gc;
        float4 d = *(const float4*)&ws[DIR_C_OFF + cell * FCH + c4 * 4];
        cs.x += d.x; cs.y += d.y; cs.z += d.z; cs.w += d.w;
        wsm  += ws[DIR_W_OFF + cell];
    }

    float s = (wsm > 0.01f) ? (1.0f / (wsm + 0.001f)) : 0.0f;
    cs.x *= s; cs.y *= s; cs.z *= s; cs.w *= s;

    size_t base = ((size_t)gr * 256 + gc) * FCH + c4 * 4;
    #pragma unroll
    for (int b = 0; b < 8; ++b) {
        *(float4*)&out[(size_t)b * (256 * 256 * FCH) + base] = cs;
    }
}

extern "C" void kernel_launch(void* const* d_in, const int* in_sizes, int n_in,
                              void* d_out, int out_size, void* d_ws, size_t ws_size,
                              hipStream_t stream) {
    const float*  f_map  = (const float*)d_in[0];
    const float2* uv_map = (const float2*)d_in[1];
    const float*  mask   = (const float*)d_in[2];
    float* out = (float*)d_out;
    float* ws  = (float*)d_ws;

    bool bucketed = ws_size >= (size_t)WS_FLOATS * sizeof(float);

    if (bucketed) {
        hipMemsetAsync(ws, 0, (size_t)ZERO_FLOATS * sizeof(float), stream);
        bin_kernel<<<(NPIX * 16) / 256, 256, 0, stream>>>(f_map, uv_map, mask, ws);
        gather_kernel<<<(NCELL * 16) / 256, 256, 0, stream>>>(f_map, ws);
    } else {
        hipMemsetAsync(ws, 0, (size_t)CNT_OFF * sizeof(float), stream);
        splat_kernel<<<(NPIX * 16) / 256, 256, 0, stream>>>(f_map, uv_map, mask, ws);
    }
    finalize_kernel<<<1024, 256, 0, stream>>>(ws, out);
}